// Round 7
// baseline (184.266 us; speedup 1.0000x reference)
//
#include <hip/hip_runtime.h>

#define NN 4096
#define IND 128
#define OUTD 64
#define WJ 128                 // j-window per wave per pipeline step
#define NWIN 8                 // windows per wave: 4 waves-per-rel * 8 * 128 = 4096 j
#define LOG2E 1.44269504088896340736f

typedef __attribute__((ext_vector_type(4))) float  floatx4;
typedef __attribute__((ext_vector_type(8))) __bf16 bf16x8;
typedef __attribute__((ext_vector_type(4))) int    intx4;

#if __has_builtin(__builtin_amdgcn_exp2f)
#define EXP2(x) __builtin_amdgcn_exp2f(x)
#else
#define EXP2(x) exp2f(x)
#endif

__device__ __forceinline__ unsigned short f2bf(float f) {
  unsigned int u = __float_as_uint(f);
  u += 0x7fffu + ((u >> 16) & 1u);   // RNE; inputs are finite
  return (unsigned short)(u >> 16);
}

// ---------------- Kernel 1: Wh = H@W + A-bitmask compression (one dispatch).
// Blocks x<256: Wh/sA/sB/whF as before. Blocks x>=256: compress 2 rows of A
// (read LINEARLY — the R4/R6 data showed scattered 512B A-reads cap at
// ~3.4 TB/s regardless of waves/depth => DRAM-locality; linear rows stream).
// PW[rel][row][wq][lj] (uint32): nibble v = bits for j = wq*1024+v*128+lj*4+0..3
__global__ __launch_bounds__(256) void gat_prep(
    const float* __restrict__ H,
    const int* __restrict__ A0, const int* __restrict__ A1,
    const float* __restrict__ W0, const float* __restrict__ W1,
    const float* __restrict__ av0, const float* __restrict__ av1,
    unsigned short* __restrict__ whF,
    float* __restrict__ sA, float* __restrict__ sB,
    unsigned* __restrict__ PW)
{
  const int rel = blockIdx.y;
  const int t = threadIdx.x;

  if (blockIdx.x >= 256) {
    // ---- A compressor: 2 rows, sequential read, LDS nibble transpose
    const int cb = blockIdx.x - 256;                 // 0..2047
    const int* __restrict__ Ar = rel ? A1 : A0;
    unsigned* __restrict__ pwr = PW + (size_t)rel * NN * 128;
    __shared__ unsigned char nib[2][4][256];
    for (int rr = 0; rr < 2; rr++) {
      const int row = cb * 2 + rr;
      const int* __restrict__ ap = Ar + (size_t)row * NN;
#pragma unroll
      for (int it = 0; it < 4; it++) {               // 1024 j per pass, coalesced
        intx4 a = *(const intx4*)(ap + it * 1024 + t * 4);
        nib[rr][it][t] = (unsigned char)((a[0] != 0) | ((a[1] != 0) << 1) |
                                         ((a[2] != 0) << 2) | ((a[3] != 0) << 3));
      }
      __syncthreads();
      if (t < 128) {                                 // assemble 128 words/row
        const int wq = t >> 5, lj = t & 31;
        unsigned wd = 0;
#pragma unroll
        for (int v = 0; v < 8; v++)
          wd |= (unsigned)nib[rr][wq][v * 32 + lj] << (4 * v);
        pwr[(size_t)row * 128 + t] = wd;             // coalesced 512B/row
      }
    }
    return;
  }

  // ---- original prep path
  const float* __restrict__ W  = rel ? W1 : W0;
  const float* __restrict__ av = rel ? av1 : av0;
  const int i0 = blockIdx.x * 16;
  const int c = t & 63;                                   // lane == output channel
  const int wv = __builtin_amdgcn_readfirstlane(t >> 6);  // wave -> 4 rows
  const float* __restrict__ hp = H + (size_t)(i0 + wv * 4) * IND;

  float acc0 = 0.f, acc1 = 0.f, acc2 = 0.f, acc3 = 0.f;
#pragma unroll 8
  for (int k = 0; k < IND; k += 4) {
    float4 h0 = *(const float4*)(hp + k);
    float4 h1 = *(const float4*)(hp + IND + k);
    float4 h2 = *(const float4*)(hp + 2 * IND + k);
    float4 h3 = *(const float4*)(hp + 3 * IND + k);
    float w0 = W[(k + 0) * OUTD + c];
    float w1 = W[(k + 1) * OUTD + c];
    float w2 = W[(k + 2) * OUTD + c];
    float w3 = W[(k + 3) * OUTD + c];
    acc0 += h0.x * w0 + h0.y * w1 + h0.z * w2 + h0.w * w3;
    acc1 += h1.x * w0 + h1.y * w1 + h1.z * w2 + h1.w * w3;
    acc2 += h2.x * w0 + h2.y * w1 + h2.z * w2 + h2.w * w3;
    acc3 += h3.x * w0 + h3.y * w1 + h3.z * w2 + h3.w * w3;
  }

  const float alo = av[c] * LOG2E, ahi = av[OUTD + c] * LOG2E;
  float pa0 = acc0 * alo, pa1 = acc1 * alo, pa2 = acc2 * alo, pa3 = acc3 * alo;
  float pb0 = acc0 * ahi, pb1 = acc1 * ahi, pb2 = acc2 * ahi, pb3 = acc3 * ahi;
#pragma unroll
  for (int off = 32; off >= 1; off >>= 1) {
    pa0 += __shfl_xor(pa0, off); pa1 += __shfl_xor(pa1, off);
    pa2 += __shfl_xor(pa2, off); pa3 += __shfl_xor(pa3, off);
    pb0 += __shfl_xor(pb0, off); pb1 += __shfl_xor(pb1, off);
    pb2 += __shfl_xor(pb2, off); pb3 += __shfl_xor(pb3, off);
  }
  const int ibase = i0 + wv * 4;
  if (c == 0) {
    float* sa = sA + rel * NN + ibase;
    float* sb = sB + rel * NN + ibase;
    sa[0] = pa0; sa[1] = pa1; sa[2] = pa2; sa[3] = pa3;
    sb[0] = pb0; sb[1] = pb1; sb[2] = pb2; sb[3] = pb3;
  }

  unsigned long long packed =
      (unsigned long long)f2bf(acc0)        | ((unsigned long long)f2bf(acc1) << 16) |
      ((unsigned long long)f2bf(acc2) << 32) | ((unsigned long long)f2bf(acc3) << 48);
  *(unsigned long long*)(whF + ((size_t)(rel * 512 + (ibase >> 3)) * 64 + c) * 8 + (ibase & 7)) = packed;
}

// ---------------- Kernel 2 (fused): R3 structure, A-stream replaced by the
// 32x-compressed PW bitmask (8 uint32/lane preloaded). No nt loads remain.
__global__ __launch_bounds__(512, 2) void gat_fused(
    const unsigned* __restrict__ PW,
    const unsigned short* __restrict__ whF,
    const float* __restrict__ sA, const float* __restrict__ sB,
    const float* __restrict__ bias,
    float* __restrict__ out)            // [4096][64]
{
  __shared__ char lds[8][2][4096];      // 8 waves x double-buffered 4 KB w-tile (64 KB)
  const int i0   = blockIdx.x * 16;
  const int t    = threadIdx.x;
  const int w    = t >> 6;              // 0..7
  const int rel  = w >> 2;              // waves 0-3 -> rel0, waves 4-7 -> rel1
  const int lane = t & 63;
  const int quad = lane >> 4;
  const int m    = lane & 15;
  const int lj   = lane & 31;           // j-quad index (4 j per lane over 128-j window)
  const int half = lane >> 5;           // row-parity selector
  const int s_st = lj >> 1;             // staging 8-j slot
  const int wboff = s_st * 256 + (lj & 1) * 8;
  const unsigned short* __restrict__ wh = whF + (size_t)rel * 512 * 64 * 8;
  const float* __restrict__ sbp = sB + rel * NN;

  // per-lane si registers — lane's stage rows are rp = 2p + half
  float si_r[8];
#pragma unroll
  for (int p = 0; p < 8; p++) si_r[p] = sA[rel * NN + i0 + 2 * p + half];

  // per-lane adjacency nibbles: pw[p] nibble(win) = A bits for this lane's 4 j
  unsigned pw[8];
  const unsigned* __restrict__ pwp =
      PW + ((size_t)(rel * NN + i0 + half) * 4 + (w & 3)) * 32 + lj;
#pragma unroll
  for (int p = 0; p < 8; p++) pw[p] = pwp[(size_t)(2 * p) * 128];

  const int jbase = (w & 3) * (NWIN * WJ);   // wave's 1024-j span within its rel

  floatx4 acc0 = {0.f,0.f,0.f,0.f}, acc1 = acc0, acc2 = acc0, acc3 = acc0, acc4 = acc0;
  bf16x8 vone;
#pragma unroll
  for (int k = 0; k < 8; k++) vone[k] = (__bf16)1.0f;

  float4 sjv2[2];                       // sB window double-buffer
  bf16x8 b[4][4];                       // current window's B fragments

  auto issueS = [&](int win) {
    sjv2[win & 1] = *(const float4*)(sbp + jbase + win * WJ + lj * 4);
  };

  auto stage = [&](int win) {           // e(win) -> LDS buf[win&1]; pure VALU now
    char* slice = lds[w][win & 1];
    const float4 sjv = sjv2[win & 1];
#pragma unroll
    for (int p = 0; p < 8; p++) {
      const int rp = 2 * p + half;
      const float si = si_r[p];
      const unsigned nb = (pw[p] >> (win * 4)) & 0xFu;
      float t0 = si + sjv.x, t1 = si + sjv.y, t2 = si + sjv.z, t3 = si + sjv.w;
      float e0 = EXP2(fmaxf(t0, 0.2f * t0));
      float e1 = EXP2(fmaxf(t1, 0.2f * t1));
      float e2 = EXP2(fmaxf(t2, 0.2f * t2));
      float e3 = EXP2(fmaxf(t3, 0.2f * t3));
      e0 = (nb & 1u) ? e0 : 0.f;
      e1 = (nb & 2u) ? e1 : 0.f;
      e2 = (nb & 4u) ? e2 : 0.f;
      e3 = (nb & 8u) ? e3 : 0.f;
      uint2 pk;
      pk.x = (unsigned)f2bf(e0) | ((unsigned)f2bf(e1) << 16);
      pk.y = (unsigned)f2bf(e2) | ((unsigned)f2bf(e3) << 16);
      *(uint2*)(slice + wboff + ((rp ^ s_st) & 15) * 16) = pk;
    }
  };

  auto issueB = [&](int win) {          // 16 lane-contiguous 16B loads from L2
    const int jw = jbase + win * WJ;
    const unsigned short* bb = wh + ((size_t)(jw >> 3) + quad) * 512 + (size_t)m * 8;
#pragma unroll
    for (int ks = 0; ks < 4; ks++)
#pragma unroll
      for (int nt = 0; nt < 4; nt++)
        b[ks][nt] = *(const bf16x8*)(bb + (size_t)ks * 2048 + nt * 128);
  };

  auto domfma = [&](int win) {          // prefetch all 4 LDS frags, then MFMA burst
    char* slice = lds[w][win & 1];
    bf16x8 afr[4];
#pragma unroll
    for (int ks = 0; ks < 4; ks++) {
      const int s = ks * 4 + quad;
      afr[ks] = *(const bf16x8*)(slice + s * 256 + ((m ^ s) & 15) * 16);
    }
#pragma unroll
    for (int ks = 0; ks < 4; ks++) {
      acc0 = __builtin_amdgcn_mfma_f32_16x16x32_bf16(afr[ks], b[ks][0], acc0, 0, 0, 0);
      acc1 = __builtin_amdgcn_mfma_f32_16x16x32_bf16(afr[ks], b[ks][1], acc1, 0, 0, 0);
      acc2 = __builtin_amdgcn_mfma_f32_16x16x32_bf16(afr[ks], b[ks][2], acc2, 0, 0, 0);
      acc3 = __builtin_amdgcn_mfma_f32_16x16x32_bf16(afr[ks], b[ks][3], acc3, 0, 0, 0);
      acc4 = __builtin_amdgcn_mfma_f32_16x16x32_bf16(afr[ks], vone,     acc4, 0, 0, 0);
    }
  };

  // ---- prime
  issueS(0); issueS(1);
  stage(0);

#pragma unroll
  for (int win = 0; win < NWIN; win++) {
    issueB(win);                           // B(win) in flight
    if (win + 2 < NWIN) issueS(win + 2);   // next-next sB window
    if (win + 1 < NWIN) stage(win + 1);    // pure VALU; covers B(win) L2 latency
    domfma(win);
  }

  // ---- epilogue: acc -> own slice0 (dead), dsum -> own slice1 (dead)
  float* redw  = (float*)lds[w][0];
  float* dredw = (float*)lds[w][1];
  // C/D layout: col = lane&15 (+16*nt), row = quad*4 + reg   [m89/m91]
#pragma unroll
  for (int r = 0; r < 4; r++) {
    const int row = quad * 4 + r;
    redw[row * 64 + 0 * 16 + m] = acc0[r];
    redw[row * 64 + 1 * 16 + m] = acc1[r];
    redw[row * 64 + 2 * 16 + m] = acc2[r];
    redw[row * 64 + 3 * 16 + m] = acc3[r];
  }
  if (m == 0) {
#pragma unroll
    for (int r = 0; r < 4; r++) dredw[quad * 4 + r] = acc4[r];
  }
  __syncthreads();

  // ---- in-block combine: both relations' partials are in LDS.
  const int c  = t & 63;
  const int r0 = t >> 6;                // 0..7
  const float bc = bias[c];
#pragma unroll
  for (int rr = r0; rr < 16; rr += 8) {
    float n0 = 0.f, n1 = 0.f, d0 = 0.f, d1 = 0.f;
#pragma unroll
    for (int ww = 0; ww < 4; ww++) {
      n0 += ((const float*)lds[ww][0])[rr * 64 + c];
      d0 += ((const float*)lds[ww][1])[rr];
      n1 += ((const float*)lds[ww + 4][0])[rr * 64 + c];
      d1 += ((const float*)lds[ww + 4][1])[rr];
    }
    const float inv0 = d0 > 0.f ? 1.f / d0 : 0.f;   // isolated-row nan_to_num -> 0
    const float inv1 = d1 > 0.f ? 1.f / d1 : 0.f;
    out[(size_t)(i0 + rr) * OUTD + c] = n0 * inv0 + n1 * inv1 + bc;
  }
}

extern "C" void kernel_launch(void* const* d_in, const int* in_sizes, int n_in,
                              void* d_out, int out_size, void* d_ws, size_t ws_size,
                              hipStream_t stream) {
  const float* H    = (const float*)d_in[0];
  const int*   A0   = (const int*)d_in[1];
  const int*   A1   = (const int*)d_in[2];
  const float* W0   = (const float*)d_in[3];
  const float* W1   = (const float*)d_in[4];
  const float* av0  = (const float*)d_in[5];
  const float* av1  = (const float*)d_in[6];
  const float* bias = (const float*)d_in[7];
  float* out = (float*)d_out;

  // ws layout: whF 1 MB | sA 32 KB | sB 32 KB | PW 4 MB
  const size_t whF_b = (size_t)2 * 512 * 64 * 8 * 2;     // 1 MB
  const size_t s_b   = (size_t)2 * NN * 4;               // 32 KB each

  unsigned short* whF = (unsigned short*)d_ws;
  float*          sA  = (float*)((char*)d_ws + whF_b);
  float*          sB  = (float*)((char*)d_ws + whF_b + s_b);
  unsigned*       PW  = (unsigned*)((char*)d_ws + whF_b + 2 * s_b);

  gat_prep<<<dim3(256 + 2048, 2), 256, 0, stream>>>(H, A0, A1, W0, W1, av0, av1,
                                                    whF, sA, sB, PW);
  gat_fused<<<NN / 16, 512, 0, stream>>>(PW, whF, sA, sB, bias, out);
}

// Round 8
// 178.788 us; speedup vs baseline: 1.0306x; 1.0306x over previous
//
#include <hip/hip_runtime.h>

#define NN 4096
#define IND 128
#define OUTD 64
#define WJ 128                 // j-window per wave per pipeline step
#define NWIN 8                 // windows per wave: 4 waves-per-rel * 8 * 128 = 4096 j
#define LOG2E 1.44269504088896340736f

typedef __attribute__((ext_vector_type(4))) float  floatx4;
typedef __attribute__((ext_vector_type(8))) __bf16 bf16x8;
typedef __attribute__((ext_vector_type(4))) int    intx4;

#if __has_builtin(__builtin_amdgcn_exp2f)
#define EXP2(x) __builtin_amdgcn_exp2f(x)
#else
#define EXP2(x) exp2f(x)
#endif

__device__ __forceinline__ unsigned short f2bf(float f) {
  unsigned int u = __float_as_uint(f);
  u += 0x7fffu + ((u >> 16) & 1u);   // RNE; inputs are finite
  return (unsigned short)(u >> 16);
}

// ---------------- Kernel 1: Wh = H@W + A-bitmask compression (one dispatch).
// Blocks x<256: Wh/sA/sB/whF (unchanged). Blocks x>=256: STREAMING compressor,
// rebuilt copy-shaped after R7 (2.65 TB/s) underperformed scattered-nt (3.4):
// 8 rows/block, 4 pipelined iters, nt loads issued one iter ahead (128B/thread
// in flight), ONE barrier/iter, all 256 threads write words. Discriminates
// "structure-limited" vs "platform read ceiling ~3.3 TB/s".
// PW[rel][row][wq][lj] (uint32): nibble v = bits for j = wq*1024+v*128+lj*4+0..3
__global__ __launch_bounds__(256) void gat_prep(
    const float* __restrict__ H,
    const int* __restrict__ A0, const int* __restrict__ A1,
    const float* __restrict__ W0, const float* __restrict__ W1,
    const float* __restrict__ av0, const float* __restrict__ av1,
    unsigned short* __restrict__ whF,
    float* __restrict__ sA, float* __restrict__ sB,
    unsigned* __restrict__ PW)
{
  const int rel = blockIdx.y;
  const int t = threadIdx.x;

  if (blockIdx.x >= 256) {
    // ---- streaming A compressor: 8 rows, reg+LDS double-buffered pipeline
    const int cb = blockIdx.x - 256;                 // 0..511
    const int* __restrict__ Ar = rel ? A1 : A0;
    unsigned* __restrict__ pwr = PW + (size_t)rel * NN * 128;
    const int r0 = cb * 8;
    __shared__ unsigned char nib[2][2][4][256];      // [buf][row01][seg][lane] 4 KB
    intx4 av[2][2][4];                               // [buf][row01][seg]

    // prologue: rows r0, r0+1 -> buf 0
#pragma unroll
    for (int rr = 0; rr < 2; rr++) {
      const int* ap = Ar + (size_t)(r0 + rr) * NN + t * 4;
#pragma unroll
      for (int s = 0; s < 4; s++)
        av[0][rr][s] = __builtin_nontemporal_load((const intx4*)(ap + s * 1024));
    }

#pragma unroll
    for (int it = 0; it < 4; it++) {
      const int buf = it & 1;
      // issue next row-pair one iteration ahead (covered by nib+write phases)
      if (it < 3) {
#pragma unroll
        for (int rr = 0; rr < 2; rr++) {
          const int* ap = Ar + (size_t)(r0 + 2 * (it + 1) + rr) * NN + t * 4;
#pragma unroll
          for (int s = 0; s < 4; s++)
            av[buf ^ 1][rr][s] =
                __builtin_nontemporal_load((const intx4*)(ap + s * 1024));
        }
      }
      // nibbles for current pair (consumes av[buf]; compiler waits only these)
#pragma unroll
      for (int rr = 0; rr < 2; rr++)
#pragma unroll
        for (int s = 0; s < 4; s++) {
          intx4 a = av[buf][rr][s];
          nib[buf][rr][s][t] =
              (unsigned char)((a[0] != 0) | ((a[1] != 0) << 1) |
                              ((a[2] != 0) << 2) | ((a[3] != 0) << 3));
        }
      __syncthreads();    // one barrier/iter; it+1's barrier protects nib reuse
      // all 256 threads write: 2 rows x 128 words, coalesced 1 KB
      const int rr   = t >> 7;                       // 0..1
      const int wd_i = t & 127;
      const int wq = wd_i >> 5, lj = wd_i & 31;
      unsigned wd = 0;
#pragma unroll
      for (int v = 0; v < 8; v++)
        wd |= (unsigned)nib[buf][rr][wq][v * 32 + lj] << (4 * v);
      pwr[(size_t)(r0 + 2 * it + rr) * 128 + wd_i] = wd;
    }
    return;
  }

  // ---- original prep path (unchanged)
  const float* __restrict__ W  = rel ? W1 : W0;
  const float* __restrict__ av = rel ? av1 : av0;
  const int i0 = blockIdx.x * 16;
  const int c = t & 63;                                   // lane == output channel
  const int wv = __builtin_amdgcn_readfirstlane(t >> 6);  // wave -> 4 rows
  const float* __restrict__ hp = H + (size_t)(i0 + wv * 4) * IND;

  float acc0 = 0.f, acc1 = 0.f, acc2 = 0.f, acc3 = 0.f;
#pragma unroll 8
  for (int k = 0; k < IND; k += 4) {
    float4 h0 = *(const float4*)(hp + k);
    float4 h1 = *(const float4*)(hp + IND + k);
    float4 h2 = *(const float4*)(hp + 2 * IND + k);
    float4 h3 = *(const float4*)(hp + 3 * IND + k);
    float w0 = W[(k + 0) * OUTD + c];
    float w1 = W[(k + 1) * OUTD + c];
    float w2 = W[(k + 2) * OUTD + c];
    float w3 = W[(k + 3) * OUTD + c];
    acc0 += h0.x * w0 + h0.y * w1 + h0.z * w2 + h0.w * w3;
    acc1 += h1.x * w0 + h1.y * w1 + h1.z * w2 + h1.w * w3;
    acc2 += h2.x * w0 + h2.y * w1 + h2.z * w2 + h2.w * w3;
    acc3 += h3.x * w0 + h3.y * w1 + h3.z * w2 + h3.w * w3;
  }

  const float alo = av[c] * LOG2E, ahi = av[OUTD + c] * LOG2E;
  float pa0 = acc0 * alo, pa1 = acc1 * alo, pa2 = acc2 * alo, pa3 = acc3 * alo;
  float pb0 = acc0 * ahi, pb1 = acc1 * ahi, pb2 = acc2 * ahi, pb3 = acc3 * ahi;
#pragma unroll
  for (int off = 32; off >= 1; off >>= 1) {
    pa0 += __shfl_xor(pa0, off); pa1 += __shfl_xor(pa1, off);
    pa2 += __shfl_xor(pa2, off); pa3 += __shfl_xor(pa3, off);
    pb0 += __shfl_xor(pb0, off); pb1 += __shfl_xor(pb1, off);
    pb2 += __shfl_xor(pb2, off); pb3 += __shfl_xor(pb3, off);
  }
  const int ibase = i0 + wv * 4;
  if (c == 0) {
    float* sa = sA + rel * NN + ibase;
    float* sb = sB + rel * NN + ibase;
    sa[0] = pa0; sa[1] = pa1; sa[2] = pa2; sa[3] = pa3;
    sb[0] = pb0; sb[1] = pb1; sb[2] = pb2; sb[3] = pb3;
  }

  unsigned long long packed =
      (unsigned long long)f2bf(acc0)        | ((unsigned long long)f2bf(acc1) << 16) |
      ((unsigned long long)f2bf(acc2) << 32) | ((unsigned long long)f2bf(acc3) << 48);
  *(unsigned long long*)(whF + ((size_t)(rel * 512 + (ibase >> 3)) * 64 + c) * 8 + (ibase & 7)) = packed;
}

// ---------------- Kernel 2 (fused): R7's proven PW-bitmask version, unchanged.
__global__ __launch_bounds__(512, 2) void gat_fused(
    const unsigned* __restrict__ PW,
    const unsigned short* __restrict__ whF,
    const float* __restrict__ sA, const float* __restrict__ sB,
    const float* __restrict__ bias,
    float* __restrict__ out)            // [4096][64]
{
  __shared__ char lds[8][2][4096];      // 8 waves x double-buffered 4 KB w-tile (64 KB)
  const int i0   = blockIdx.x * 16;
  const int t    = threadIdx.x;
  const int w    = t >> 6;              // 0..7
  const int rel  = w >> 2;              // waves 0-3 -> rel0, waves 4-7 -> rel1
  const int lane = t & 63;
  const int quad = lane >> 4;
  const int m    = lane & 15;
  const int lj   = lane & 31;           // j-quad index (4 j per lane over 128-j window)
  const int half = lane >> 5;           // row-parity selector
  const int s_st = lj >> 1;             // staging 8-j slot
  const int wboff = s_st * 256 + (lj & 1) * 8;
  const unsigned short* __restrict__ wh = whF + (size_t)rel * 512 * 64 * 8;
  const float* __restrict__ sbp = sB + rel * NN;

  // per-lane si registers — lane's stage rows are rp = 2p + half
  float si_r[8];
#pragma unroll
  for (int p = 0; p < 8; p++) si_r[p] = sA[rel * NN + i0 + 2 * p + half];

  // per-lane adjacency nibbles: pw[p] nibble(win) = A bits for this lane's 4 j
  unsigned pw[8];
  const unsigned* __restrict__ pwp =
      PW + ((size_t)(rel * NN + i0 + half) * 4 + (w & 3)) * 32 + lj;
#pragma unroll
  for (int p = 0; p < 8; p++) pw[p] = pwp[(size_t)(2 * p) * 128];

  const int jbase = (w & 3) * (NWIN * WJ);   // wave's 1024-j span within its rel

  floatx4 acc0 = {0.f,0.f,0.f,0.f}, acc1 = acc0, acc2 = acc0, acc3 = acc0, acc4 = acc0;
  bf16x8 vone;
#pragma unroll
  for (int k = 0; k < 8; k++) vone[k] = (__bf16)1.0f;

  float4 sjv2[2];                       // sB window double-buffer
  bf16x8 b[4][4];                       // current window's B fragments

  auto issueS = [&](int win) {
    sjv2[win & 1] = *(const float4*)(sbp + jbase + win * WJ + lj * 4);
  };

  auto stage = [&](int win) {           // e(win) -> LDS buf[win&1]; pure VALU now
    char* slice = lds[w][win & 1];
    const float4 sjv = sjv2[win & 1];
#pragma unroll
    for (int p = 0; p < 8; p++) {
      const int rp = 2 * p + half;
      const float si = si_r[p];
      const unsigned nb = (pw[p] >> (win * 4)) & 0xFu;
      float t0 = si + sjv.x, t1 = si + sjv.y, t2 = si + sjv.z, t3 = si + sjv.w;
      float e0 = EXP2(fmaxf(t0, 0.2f * t0));
      float e1 = EXP2(fmaxf(t1, 0.2f * t1));
      float e2 = EXP2(fmaxf(t2, 0.2f * t2));
      float e3 = EXP2(fmaxf(t3, 0.2f * t3));
      e0 = (nb & 1u) ? e0 : 0.f;
      e1 = (nb & 2u) ? e1 : 0.f;
      e2 = (nb & 4u) ? e2 : 0.f;
      e3 = (nb & 8u) ? e3 : 0.f;
      uint2 pk;
      pk.x = (unsigned)f2bf(e0) | ((unsigned)f2bf(e1) << 16);
      pk.y = (unsigned)f2bf(e2) | ((unsigned)f2bf(e3) << 16);
      *(uint2*)(slice + wboff + ((rp ^ s_st) & 15) * 16) = pk;
    }
  };

  auto issueB = [&](int win) {          // 16 lane-contiguous 16B loads from L2
    const int jw = jbase + win * WJ;
    const unsigned short* bb = wh + ((size_t)(jw >> 3) + quad) * 512 + (size_t)m * 8;
#pragma unroll
    for (int ks = 0; ks < 4; ks++)
#pragma unroll
      for (int nt = 0; nt < 4; nt++)
        b[ks][nt] = *(const bf16x8*)(bb + (size_t)ks * 2048 + nt * 128);
  };

  auto domfma = [&](int win) {          // prefetch all 4 LDS frags, then MFMA burst
    char* slice = lds[w][win & 1];
    bf16x8 afr[4];
#pragma unroll
    for (int ks = 0; ks < 4; ks++) {
      const int s = ks * 4 + quad;
      afr[ks] = *(const bf16x8*)(slice + s * 256 + ((m ^ s) & 15) * 16);
    }
#pragma unroll
    for (int ks = 0; ks < 4; ks++) {
      acc0 = __builtin_amdgcn_mfma_f32_16x16x32_bf16(afr[ks], b[ks][0], acc0, 0, 0, 0);
      acc1 = __builtin_amdgcn_mfma_f32_16x16x32_bf16(afr[ks], b[ks][1], acc1, 0, 0, 0);
      acc2 = __builtin_amdgcn_mfma_f32_16x16x32_bf16(afr[ks], b[ks][2], acc2, 0, 0, 0);
      acc3 = __builtin_amdgcn_mfma_f32_16x16x32_bf16(afr[ks], b[ks][3], acc3, 0, 0, 0);
      acc4 = __builtin_amdgcn_mfma_f32_16x16x32_bf16(afr[ks], vone,     acc4, 0, 0, 0);
    }
  };

  // ---- prime
  issueS(0); issueS(1);
  stage(0);

#pragma unroll
  for (int win = 0; win < NWIN; win++) {
    issueB(win);                           // B(win) in flight
    if (win + 2 < NWIN) issueS(win + 2);   // next-next sB window
    if (win + 1 < NWIN) stage(win + 1);    // pure VALU; covers B(win) L2 latency
    domfma(win);
  }

  // ---- epilogue: acc -> own slice0 (dead), dsum -> own slice1 (dead)
  float* redw  = (float*)lds[w][0];
  float* dredw = (float*)lds[w][1];
  // C/D layout: col = lane&15 (+16*nt), row = quad*4 + reg   [m89/m91]
#pragma unroll
  for (int r = 0; r < 4; r++) {
    const int row = quad * 4 + r;
    redw[row * 64 + 0 * 16 + m] = acc0[r];
    redw[row * 64 + 1 * 16 + m] = acc1[r];
    redw[row * 64 + 2 * 16 + m] = acc2[r];
    redw[row * 64 + 3 * 16 + m] = acc3[r];
  }
  if (m == 0) {
#pragma unroll
    for (int r = 0; r < 4; r++) dredw[quad * 4 + r] = acc4[r];
  }
  __syncthreads();

  // ---- in-block combine: both relations' partials are in LDS.
  const int c  = t & 63;
  const int r0 = t >> 6;                // 0..7
  const float bc = bias[c];
#pragma unroll
  for (int rr = r0; rr < 16; rr += 8) {
    float n0 = 0.f, n1 = 0.f, d0 = 0.f, d1 = 0.f;
#pragma unroll
    for (int ww = 0; ww < 4; ww++) {
      n0 += ((const float*)lds[ww][0])[rr * 64 + c];
      d0 += ((const float*)lds[ww][1])[rr];
      n1 += ((const float*)lds[ww + 4][0])[rr * 64 + c];
      d1 += ((const float*)lds[ww + 4][1])[rr];
    }
    const float inv0 = d0 > 0.f ? 1.f / d0 : 0.f;   // isolated-row nan_to_num -> 0
    const float inv1 = d1 > 0.f ? 1.f / d1 : 0.f;
    out[(size_t)(i0 + rr) * OUTD + c] = n0 * inv0 + n1 * inv1 + bc;
  }
}

extern "C" void kernel_launch(void* const* d_in, const int* in_sizes, int n_in,
                              void* d_out, int out_size, void* d_ws, size_t ws_size,
                              hipStream_t stream) {
  const float* H    = (const float*)d_in[0];
  const int*   A0   = (const int*)d_in[1];
  const int*   A1   = (const int*)d_in[2];
  const float* W0   = (const float*)d_in[3];
  const float* W1   = (const float*)d_in[4];
  const float* av0  = (const float*)d_in[5];
  const float* av1  = (const float*)d_in[6];
  const float* bias = (const float*)d_in[7];
  float* out = (float*)d_out;

  // ws layout: whF 1 MB | sA 32 KB | sB 32 KB | PW 4 MB
  const size_t whF_b = (size_t)2 * 512 * 64 * 8 * 2;     // 1 MB
  const size_t s_b   = (size_t)2 * NN * 4;               // 32 KB each

  unsigned short* whF = (unsigned short*)d_ws;
  float*          sA  = (float*)((char*)d_ws + whF_b);
  float*          sB  = (float*)((char*)d_ws + whF_b + s_b);
  unsigned*       PW  = (unsigned*)((char*)d_ws + whF_b + 2 * s_b);

  gat_prep<<<dim3(256 + 512, 2), 256, 0, stream>>>(H, A0, A1, W0, W1, av0, av1,
                                                   whF, sA, sB, PW);
  gat_fused<<<NN / 16, 512, 0, stream>>>(PW, whF, sA, sB, bias, out);
}

// Round 9
// 174.543 us; speedup vs baseline: 1.0557x; 1.0243x over previous
//
#include <hip/hip_runtime.h>

#define NN 4096
#define IND 128
#define OUTD 64
#define WJ 128                 // j-window per wave per pipeline step
#define NWIN 8                 // windows per wave: 4 waves-per-rel * 8 * 128 = 4096 j
#define LOG2E 1.44269504088896340736f

typedef __attribute__((ext_vector_type(4))) float  floatx4;
typedef __attribute__((ext_vector_type(8))) __bf16 bf16x8;
typedef __attribute__((ext_vector_type(4))) int    intx4;

#if __has_builtin(__builtin_amdgcn_exp2f)
#define EXP2(x) __builtin_amdgcn_exp2f(x)
#else
#define EXP2(x) exp2f(x)
#endif

__device__ __forceinline__ unsigned short f2bf(float f) {
  unsigned int u = __float_as_uint(f);
  u += 0x7fffu + ((u >> 16) & 1u);   // RNE; inputs are finite
  return (unsigned short)(u >> 16);
}

// ---------------- Kernel 1: Wh = H@W (fp32), s_a/s_b (log2e-scaled), whF bf16.
// whF is FRAGMENT-MAJOR: element (node j, channel c) at ((rel*512 + (j>>3))*64 + c)*8 + (j&7)
__global__ __launch_bounds__(256) void gat_prep(
    const float* __restrict__ H,
    const float* __restrict__ W0, const float* __restrict__ W1,
    const float* __restrict__ av0, const float* __restrict__ av1,
    unsigned short* __restrict__ whF,
    float* __restrict__ sA, float* __restrict__ sB)
{
  const int rel = blockIdx.y;
  const float* __restrict__ W  = rel ? W1 : W0;
  const float* __restrict__ av = rel ? av1 : av0;
  const int i0 = blockIdx.x * 16;
  const int t = threadIdx.x;
  const int c = t & 63;                                   // lane == output channel
  const int wv = __builtin_amdgcn_readfirstlane(t >> 6);  // wave -> 4 rows
  const float* __restrict__ hp = H + (size_t)(i0 + wv * 4) * IND;

  float acc0 = 0.f, acc1 = 0.f, acc2 = 0.f, acc3 = 0.f;
#pragma unroll 8
  for (int k = 0; k < IND; k += 4) {
    float4 h0 = *(const float4*)(hp + k);
    float4 h1 = *(const float4*)(hp + IND + k);
    float4 h2 = *(const float4*)(hp + 2 * IND + k);
    float4 h3 = *(const float4*)(hp + 3 * IND + k);
    float w0 = W[(k + 0) * OUTD + c];
    float w1 = W[(k + 1) * OUTD + c];
    float w2 = W[(k + 2) * OUTD + c];
    float w3 = W[(k + 3) * OUTD + c];
    acc0 += h0.x * w0 + h0.y * w1 + h0.z * w2 + h0.w * w3;
    acc1 += h1.x * w0 + h1.y * w1 + h1.z * w2 + h1.w * w3;
    acc2 += h2.x * w0 + h2.y * w1 + h2.z * w2 + h2.w * w3;
    acc3 += h3.x * w0 + h3.y * w1 + h3.z * w2 + h3.w * w3;
  }

  const float alo = av[c] * LOG2E, ahi = av[OUTD + c] * LOG2E;
  float pa0 = acc0 * alo, pa1 = acc1 * alo, pa2 = acc2 * alo, pa3 = acc3 * alo;
  float pb0 = acc0 * ahi, pb1 = acc1 * ahi, pb2 = acc2 * ahi, pb3 = acc3 * ahi;
#pragma unroll
  for (int off = 32; off >= 1; off >>= 1) {
    pa0 += __shfl_xor(pa0, off); pa1 += __shfl_xor(pa1, off);
    pa2 += __shfl_xor(pa2, off); pa3 += __shfl_xor(pa3, off);
    pb0 += __shfl_xor(pb0, off); pb1 += __shfl_xor(pb1, off);
    pb2 += __shfl_xor(pb2, off); pb3 += __shfl_xor(pb3, off);
  }
  const int ibase = i0 + wv * 4;
  if (c == 0) {
    float* sa = sA + rel * NN + ibase;
    float* sb = sB + rel * NN + ibase;
    sa[0] = pa0; sa[1] = pa1; sa[2] = pa2; sa[3] = pa3;
    sb[0] = pb0; sb[1] = pb1; sb[2] = pb2; sb[3] = pb3;
  }

  unsigned long long packed =
      (unsigned long long)f2bf(acc0)        | ((unsigned long long)f2bf(acc1) << 16) |
      ((unsigned long long)f2bf(acc2) << 32) | ((unsigned long long)f2bf(acc3) << 48);
  *(unsigned long long*)(whF + ((size_t)(rel * 512 + (ibase >> 3)) * 64 + c) * 8 + (ibase & 7)) = packed;
}

// ---------------- Kernel 2 (fused, BOTH relations per block): 512 threads =
// 8 waves; waves 0-3 rel0, waves 4-7 rel1 — the session-best R3 structure
// (174.8us). A-read hosted here (scattered nt rows): its ~3.4 TB/s ceiling
// hides the B-stream + MFMA + stage work under it. In-block combine at the
// tail; 2 dispatches total, no cross-block sync.
__global__ __launch_bounds__(512, 2) void gat_fused(
    const int* __restrict__ A0, const int* __restrict__ A1,
    const unsigned short* __restrict__ whF,
    const float* __restrict__ sA, const float* __restrict__ sB,
    const float* __restrict__ bias,
    float* __restrict__ out)            // [4096][64]
{
  __shared__ char lds[8][2][4096];      // 8 waves x double-buffered 4 KB w-tile (64 KB)
  const int i0   = blockIdx.x * 16;
  const int t    = threadIdx.x;
  const int w    = t >> 6;              // 0..7
  const int rel  = w >> 2;              // waves 0-3 -> rel0, waves 4-7 -> rel1
  const int lane = t & 63;
  const int quad = lane >> 4;
  const int m    = lane & 15;
  const int lj   = lane & 31;           // j-quad index (4 j per lane over 128-j window)
  const int half = lane >> 5;           // row-parity selector
  const int s_st = lj >> 1;             // staging 8-j slot
  const int wboff = s_st * 256 + (lj & 1) * 8;
  const int* __restrict__ A = rel ? A1 : A0;
  const unsigned short* __restrict__ wh = whF + (size_t)rel * 512 * 64 * 8;
  const float* __restrict__ sbp = sB + rel * NN;

  // per-lane si registers — lane's stage rows are rp = 2p + half
  float si_r[8];
#pragma unroll
  for (int p = 0; p < 8; p++) si_r[p] = sA[rel * NN + i0 + 2 * p + half];

  const int jbase = (w & 3) * (NWIN * WJ);   // wave's 1024-j span within its rel

  floatx4 acc0 = {0.f,0.f,0.f,0.f}, acc1 = acc0, acc2 = acc0, acc3 = acc0, acc4 = acc0;
  bf16x8 vone;
#pragma unroll
  for (int k = 0; k < 8; k++) vone[k] = (__bf16)1.0f;

  intx4  av2[2][8];                     // A double-buffer (one consumed, one in flight)
  float4 sjv2[2];
  bf16x8 b[4][4];                       // current window's B fragments

  auto issueA = [&](int win) {          // nontemporal: R5 A/B proved nt is ~16us better
    const int jw = jbase + win * WJ;
    const int buf = win & 1;
    sjv2[buf] = *(const float4*)(sbp + jw + lj * 4);
    const int* pA = A + (size_t)(i0 + half) * NN + jw + lj * 4;
#pragma unroll
    for (int p = 0; p < 8; p++)
      av2[buf][p] = __builtin_nontemporal_load((const intx4*)(pA + (size_t)(2 * p) * NN));
  };

  auto stage = [&](int win) {           // e(win) -> LDS buf[win&1]; pure VALU
    const int buf = win & 1;
    char* slice = lds[w][buf];
    const float4 sjv = sjv2[buf];
#pragma unroll
    for (int p = 0; p < 8; p++) {
      const int rp = 2 * p + half;
      const float si = si_r[p];
      float t0 = si + sjv.x, t1 = si + sjv.y, t2 = si + sjv.z, t3 = si + sjv.w;
      float e0 = EXP2(fmaxf(t0, 0.2f * t0));
      float e1 = EXP2(fmaxf(t1, 0.2f * t1));
      float e2 = EXP2(fmaxf(t2, 0.2f * t2));
      float e3 = EXP2(fmaxf(t3, 0.2f * t3));
      const intx4 a4 = av2[buf][p];
      e0 = a4[0] ? e0 : 0.f;
      e1 = a4[1] ? e1 : 0.f;
      e2 = a4[2] ? e2 : 0.f;
      e3 = a4[3] ? e3 : 0.f;
      uint2 pk;
      pk.x = (unsigned)f2bf(e0) | ((unsigned)f2bf(e1) << 16);
      pk.y = (unsigned)f2bf(e2) | ((unsigned)f2bf(e3) << 16);
      *(uint2*)(slice + wboff + ((rp ^ s_st) & 15) * 16) = pk;
    }
  };

  auto issueB = [&](int win) {          // 16 lane-contiguous 16B loads from L2
    const int jw = jbase + win * WJ;
    const unsigned short* bb = wh + ((size_t)(jw >> 3) + quad) * 512 + (size_t)m * 8;
#pragma unroll
    for (int ks = 0; ks < 4; ks++)
#pragma unroll
      for (int nt = 0; nt < 4; nt++)
        b[ks][nt] = *(const bf16x8*)(bb + (size_t)ks * 2048 + nt * 128);
  };

  auto domfma = [&](int win) {          // prefetch all 4 LDS frags, then MFMA burst
    char* slice = lds[w][win & 1];
    bf16x8 afr[4];
#pragma unroll
    for (int ks = 0; ks < 4; ks++) {
      const int s = ks * 4 + quad;
      afr[ks] = *(const bf16x8*)(slice + s * 256 + ((m ^ s) & 15) * 16);
    }
#pragma unroll
    for (int ks = 0; ks < 4; ks++) {
      acc0 = __builtin_amdgcn_mfma_f32_16x16x32_bf16(afr[ks], b[ks][0], acc0, 0, 0, 0);
      acc1 = __builtin_amdgcn_mfma_f32_16x16x32_bf16(afr[ks], b[ks][1], acc1, 0, 0, 0);
      acc2 = __builtin_amdgcn_mfma_f32_16x16x32_bf16(afr[ks], b[ks][2], acc2, 0, 0, 0);
      acc3 = __builtin_amdgcn_mfma_f32_16x16x32_bf16(afr[ks], b[ks][3], acc3, 0, 0, 0);
      acc4 = __builtin_amdgcn_mfma_f32_16x16x32_bf16(afr[ks], vone,     acc4, 0, 0, 0);
    }
  };

  // ---- prime the pipeline
  issueA(0);
  stage(0);
  issueA(1);

#pragma unroll
  for (int win = 0; win < NWIN; win++) {
    issueB(win);                           // B(win) in flight
    if (win + 2 < NWIN) issueA(win + 2);   // A(win+2): covered by stage+mfma+issueB
    if (win + 1 < NWIN) stage(win + 1);    // consumes A(win+1); covers B(win) latency
    domfma(win);
  }

  // ---- epilogue: acc -> own slice0 (dead), dsum -> own slice1 (dead)
  float* redw  = (float*)lds[w][0];
  float* dredw = (float*)lds[w][1];
  // C/D layout: col = lane&15 (+16*nt), row = quad*4 + reg   [m89/m91]
#pragma unroll
  for (int r = 0; r < 4; r++) {
    const int row = quad * 4 + r;
    redw[row * 64 + 0 * 16 + m] = acc0[r];
    redw[row * 64 + 1 * 16 + m] = acc1[r];
    redw[row * 64 + 2 * 16 + m] = acc2[r];
    redw[row * 64 + 3 * 16 + m] = acc3[r];
  }
  if (m == 0) {
#pragma unroll
    for (int r = 0; r < 4; r++) dredw[quad * 4 + r] = acc4[r];
  }
  __syncthreads();

  // ---- in-block combine: both relations' partials are in LDS.
  // 512 threads cover 16 rows x 64 ch, 2 rows/thread.
  const int c  = t & 63;
  const int r0 = t >> 6;                // 0..7
  const float bc = bias[c];
#pragma unroll
  for (int rr = r0; rr < 16; rr += 8) {
    float n0 = 0.f, n1 = 0.f, d0 = 0.f, d1 = 0.f;
#pragma unroll
    for (int ww = 0; ww < 4; ww++) {
      n0 += ((const float*)lds[ww][0])[rr * 64 + c];
      d0 += ((const float*)lds[ww][1])[rr];
      n1 += ((const float*)lds[ww + 4][0])[rr * 64 + c];
      d1 += ((const float*)lds[ww + 4][1])[rr];
    }
    const float inv0 = d0 > 0.f ? 1.f / d0 : 0.f;   // isolated-row nan_to_num -> 0
    const float inv1 = d1 > 0.f ? 1.f / d1 : 0.f;
    out[(size_t)(i0 + rr) * OUTD + c] = n0 * inv0 + n1 * inv1 + bc;
  }
}

extern "C" void kernel_launch(void* const* d_in, const int* in_sizes, int n_in,
                              void* d_out, int out_size, void* d_ws, size_t ws_size,
                              hipStream_t stream) {
  const float* H    = (const float*)d_in[0];
  const int*   A0   = (const int*)d_in[1];
  const int*   A1   = (const int*)d_in[2];
  const float* W0   = (const float*)d_in[3];
  const float* W1   = (const float*)d_in[4];
  const float* av0  = (const float*)d_in[5];
  const float* av1  = (const float*)d_in[6];
  const float* bias = (const float*)d_in[7];
  float* out = (float*)d_out;

  // ws layout: whF 1 MB | sA 32 KB | sB 32 KB
  const size_t whF_b = (size_t)2 * 512 * 64 * 8 * 2;     // 1 MB
  const size_t s_b   = (size_t)2 * NN * 4;               // 32 KB each

  unsigned short* whF = (unsigned short*)d_ws;
  float*          sA  = (float*)((char*)d_ws + whF_b);
  float*          sB  = (float*)((char*)d_ws + whF_b + s_b);

  gat_prep<<<dim3(NN / 16, 2), 256, 0, stream>>>(H, W0, W1, av0, av1, whF, sA, sB);
  gat_fused<<<NN / 16, 512, 0, stream>>>(A0, A1, whF, sA, sB, bias, out);
}